// Round 11
// baseline (306.607 us; speedup 1.0000x reference)
//
#include <hip/hip_runtime.h>
#include <hip/hip_bf16.h>

#define NN 4096
#define FIN 512
#define FOUT 64
#define NH 8
#define ALPHA 0.2f

typedef unsigned int uint;
typedef unsigned short ushort;
typedef unsigned char uchar;
typedef unsigned long long ull;
typedef __attribute__((ext_vector_type(8))) short short8;
typedef __attribute__((ext_vector_type(4))) float floatx4;

__device__ __forceinline__ float bf2f(ushort s) { return __uint_as_float(((uint)s) << 16); }
__device__ __forceinline__ ushort f2bf(float f) {
    uint u = __float_as_uint(f);
    u += 0x7fffu + ((u >> 16) & 1u);   // RNE
    return (ushort)(u >> 16);
}

// inline dtype probe: wave-uniform, deterministic (same 64 samples everywhere)
__device__ __forceinline__ int detect_bf16(const ushort* __restrict__ hraw) {
    int lane = threadIdx.x & 63;
    float a = fabsf(bf2f(hraw[2 * lane]));
    ull bal = __ballot(a >= 1e-3f && a <= 100.0f);
    return __popcll(bal) >= 32;
}

// ---------------------------------------------------------------------------
// Fused prep: [0,8192) packmask | [8192,9216) convert h (8 elem/thread) |
//             [9216,9248) transw   (unchanged from passing rounds)
// ---------------------------------------------------------------------------
#define PM_BLKS 8192
#define CV_BLKS 1024
#define TW_BLKS 32

__global__ __launch_bounds__(256) void prep_kernel(
    const int* __restrict__ mask, uchar* __restrict__ mb,
    const void* __restrict__ hraw, ushort* __restrict__ bh,
    const void* __restrict__ Wraw, ushort* __restrict__ WT)
{
    const int b = blockIdx.x, t = threadIdx.x;
    if (b < PM_BLKS) {
        size_t gid = (size_t)b * 256 + t;
        const int* p = mask + gid * 8;
        int4 aa = *(const int4*)p;
        int4 bb = *(const int4*)(p + 4);
        uint by = (uint)(aa.x > 0)        | ((uint)(aa.y > 0) << 1)
                | ((uint)(aa.z > 0) << 2) | ((uint)(aa.w > 0) << 3)
                | ((uint)(bb.x > 0) << 4) | ((uint)(bb.y > 0) << 5)
                | ((uint)(bb.z > 0) << 6) | ((uint)(bb.w > 0) << 7);
        mb[gid] = (uchar)by;
    } else if (b < PM_BLKS + CV_BLKS) {
        int isbf = detect_bf16((const ushort*)hraw);
        size_t e0 = ((size_t)(b - PM_BLKS) * 256 + t) * 8;
        if (isbf) {
            *(uint4*)(bh + e0) = *(const uint4*)((const ushort*)hraw + e0);
        } else {
            const float* s = (const float*)hraw + e0;
            float4 f0 = *(const float4*)s;
            float4 f1 = *(const float4*)(s + 4);
            uint4 o;
            o.x = (uint)f2bf(f0.x) | ((uint)f2bf(f0.y) << 16);
            o.y = (uint)f2bf(f0.z) | ((uint)f2bf(f0.w) << 16);
            o.z = (uint)f2bf(f1.x) | ((uint)f2bf(f1.y) << 16);
            o.w = (uint)f2bf(f1.z) | ((uint)f2bf(f1.w) << 16);
            *(uint4*)(bh + e0) = o;
        }
    } else {
        int isbf = detect_bf16((const ushort*)hraw);
        int b2 = b - PM_BLKS - CV_BLKS;
        int h = b2 >> 2, kq = b2 & 3;
        int o = t & 63, sub = t >> 6;
        int kbase = kq * 128 + sub * 32;
        uint pk[16];
#pragma unroll
        for (int kk = 0; kk < 32; kk += 2) {
            float v0, v1;
            size_t s0 = ((size_t)h * FIN + kbase + kk) * FOUT + o;
            size_t s1 = s0 + FOUT;
            if (isbf) { v0 = bf2f(((const ushort*)Wraw)[s0]); v1 = bf2f(((const ushort*)Wraw)[s1]); }
            else      { v0 = ((const float*)Wraw)[s0];        v1 = ((const float*)Wraw)[s1]; }
            pk[kk >> 1] = (uint)f2bf(v0) | ((uint)f2bf(v1) << 16);
        }
        ushort* dst = WT + ((size_t)h * FOUT + o) * FIN + kbase;
#pragma unroll
        for (int q = 0; q < 4; q++)
            *(uint4*)(dst + q * 8) = make_uint4(pk[q*4], pk[q*4+1], pk[q*4+2], pk[q*4+3]);
    }
}

// per-head tables: Kh = max_j er'; v_j = e^{er-Kh}; z_j = e^{alpha(er-Kh)}
__global__ __launch_bounds__(256) void khv_kernel(const float* __restrict__ er,
                                                  float* __restrict__ Kh,
                                                  float* __restrict__ vt,
                                                  float* __restrict__ zt) {
    __shared__ float red[256];
    int h = blockIdx.x >> 3, sl = blockIdx.x & 7, t = threadIdx.x;
    float m = -3.0e38f;
    for (int j = t; j < NN; j += 256) m = fmaxf(m, er[(size_t)h * NN + j]);
    red[t] = m;
    __syncthreads();
    for (int s = 128; s >= 1; s >>= 1) {
        if (t < s) red[t] = fmaxf(red[t], red[t + s]);
        __syncthreads();
    }
    float kh = red[0];
    if (t == 0 && sl == 0) Kh[h] = kh;
    int j = sl * 512 + t;
#pragma unroll
    for (int q = 0; q < 2; q++, j += 256) {
        float d = er[(size_t)h * NN + j] - kh;
        vt[(size_t)h * NN + j] = __expf(d);
        zt[(size_t)h * NN + j] = __expf(ALPHA * d);
    }
}

// ---------------------------------------------------------------------------
// Stage 1 (MFMA): Wh = h*W + bW; WhT[h][o][n] bf16; el/er dots (unchanged)
// ---------------------------------------------------------------------------
__global__ __launch_bounds__(256) void wh_kernel(
    const ushort* __restrict__ hmat, const ushort* __restrict__ WT,
    const void* __restrict__ bWr, const void* __restrict__ alr,
    const void* __restrict__ arr, const void* __restrict__ bAr,
    const ushort* __restrict__ hraw,
    ushort* __restrict__ WhT, float* __restrict__ el, float* __restrict__ er)
{
    __shared__ __align__(16) ushort sT[64][72];
    const int t = threadIdx.x, lane = t & 63, wid = t >> 6;
    const int head = blockIdx.y, rbase = blockIdx.x * 64;
    const int lm = lane & 15, lq = lane >> 4;

    floatx4 C[4];
#pragma unroll
    for (int cg = 0; cg < 4; cg++) C[cg] = (floatx4){0.f, 0.f, 0.f, 0.f};

    const ushort* Ap = hmat + (size_t)(rbase + wid * 16 + lm) * FIN + lq * 8;
    const ushort* Bp = WT + (size_t)head * FOUT * FIN + (size_t)lm * FIN + lq * 8;

#pragma unroll
    for (int kc = 0; kc < 16; kc++) {
        short8 a = *(const short8*)(Ap + kc * 32);
#pragma unroll
        for (int cg = 0; cg < 4; cg++) {
            short8 b = *(const short8*)(Bp + (size_t)cg * 16 * FIN + kc * 32);
            C[cg] = __builtin_amdgcn_mfma_f32_16x16x32_bf16(a, b, C[cg], 0, 0, 0);
        }
    }

    const int isbf = detect_bf16(hraw);
    float bA = isbf ? bf2f(((const ushort*)bAr)[head]) : ((const float*)bAr)[head];
    float pel[4] = {0.f, 0.f, 0.f, 0.f}, per[4] = {0.f, 0.f, 0.f, 0.f};
#pragma unroll
    for (int cg = 0; cg < 4; cg++) {
        int o = head * FOUT + cg * 16 + lm;
        float bw = isbf ? bf2f(((const ushort*)bWr)[o]) : ((const float*)bWr)[o];
        float av = isbf ? bf2f(((const ushort*)alr)[o]) : ((const float*)alr)[o];
        float rv = isbf ? bf2f(((const ushort*)arr)[o]) : ((const float*)arr)[o];
        ushort pk[4];
#pragma unroll
        for (int r = 0; r < 4; r++) {
            float v = C[cg][r] + bw;
            pel[r] += v * av;
            per[r] += v * rv;
            pk[r] = f2bf(v);
        }
        ushort4 p4; p4.x = pk[0]; p4.y = pk[1]; p4.z = pk[2]; p4.w = pk[3];
        *(ushort4*)(&sT[cg * 16 + lm][wid * 16 + lq * 4]) = p4;
    }
#pragma unroll
    for (int off = 1; off < 16; off <<= 1) {
#pragma unroll
        for (int r = 0; r < 4; r++) {
            pel[r] += __shfl_xor(pel[r], off);
            per[r] += __shfl_xor(per[r], off);
        }
    }
    if (lm == 0) {
#pragma unroll
        for (int r = 0; r < 4; r++) {
            int row = rbase + wid * 16 + lq * 4 + r;
            el[(size_t)head * NN + row] = pel[r];
            er[(size_t)head * NN + row] = per[r] + bA;
        }
    }
    __syncthreads();
    {
        int o = t >> 2, ch = t & 3;
        uint4 v0 = *(const uint4*)(&sT[o][ch * 16]);
        uint4 v1 = *(const uint4*)(&sT[o][ch * 16 + 8]);
        ushort* d = WhT + ((size_t)head * FOUT + o) * NN + rbase + ch * 16;
        *(uint4*)d = v0;
        *(uint4*)(d + 8) = v1;
    }
}

// ---------------------------------------------------------------------------
// Stage 2 (R11): R8 pipeline with (a) v/z read from global (L1-resident
// 16 KB/head tables — offloads the saturated LDS pipe), (b) i-tile 32,
// 128-thread blocks, grid 1024 -> 4 barrier-independent blocks/CU
// (R8 was grid-capped at 2). Math/layout byte-identical to R8.
// ---------------------------------------------------------------------------
__device__ __forceinline__ uint ppair(float v0, float v1, float z0, float z1,
                                      uint m2, float ui, float wi, float ti) {
    float p0 = (v0 >= ti) ? ui * v0 : wi * z0;
    float p1 = (v1 >= ti) ? ui * v1 : wi * z1;
    uint k0 = (uint)0 - (m2 & 1u);
    uint k1 = (uint)0 - ((m2 >> 1) & 1u);
    p0 = __uint_as_float(__float_as_uint(p0) & k0);
    p1 = __uint_as_float(__float_as_uint(p1) & k1);
    __hip_bfloat162 r = __float22bfloat162_rn(make_float2(p0, p1));
    return *(uint*)&r;
}

__device__ __forceinline__ short8 pgen8(float4 va, float4 vb, float4 za, float4 zb,
                                        uint mby, float ui, float wi, float ti) {
    union { uint4 u; short8 s; } c;
    c.u.x = ppair(va.x, va.y, za.x, za.y, mby,      ui, wi, ti);
    c.u.y = ppair(va.z, va.w, za.z, za.w, mby >> 2, ui, wi, ti);
    c.u.z = ppair(vb.x, vb.y, zb.x, zb.y, mby >> 4, ui, wi, ti);
    c.u.w = ppair(vb.z, vb.w, zb.z, zb.w, mby >> 6, ui, wi, ti);
    return c.s;
}

__global__ __launch_bounds__(128, 2) void attn_kernel(
    const uchar* __restrict__ mb,      // [NN][512] bitmask
    const ushort* __restrict__ WhT,    // [H][FOUT][NN] bf16
    const float* __restrict__ el, const float* __restrict__ Kh,
    const float* __restrict__ vt, const float* __restrict__ zt,
    const ushort* __restrict__ hraw,
    void* __restrict__ outv)
{
    __shared__ __align__(16) ushort sB[2][64 * 72];  // B tile [o][j], dbuf

    const int t = threadIdx.x, lane = t & 63, wid = t >> 6;  // wid 0..1
    const int b = blockIdx.x;
    const int head = b & 7;                        // XCD swizzle
    const int ibase = (b >> 3) * 32;               // 32 i-rows per block
    const int lm = lane & 15, lq = lane >> 4, sh8 = lq * 8;

    // per-lane row constants
    const float kh = Kh[head];
    const int myrow = ibase + wid * 16 + lm;
    const float x = el[(size_t)head * NN + myrow] + kh;
    const float Mi = fmaxf(x, ALPHA * x);
    const float ui = __expf(x - Mi);
    const float wi = __expf(ALPHA * x - Mi);
    const float ti = __expf(-x);

    const float* vp = vt + (size_t)head * NN;      // L1-resident (16 KB)
    const float* zp = zt + (size_t)head * NN;
    const uchar* mrow = mb + (size_t)myrow * 512;

    // staging: thread t -> B row so = t>>1, 32-j half sc (64 B = 4 uint4)
    const int so = t >> 1, sc = (t & 1) * 32;
    const ushort* gB = WhT + ((size_t)head * FOUT + so) * NN + sc;
    uint4 rB[4]; uint2 mkS;

    auto gload = [&](int j0) {
#pragma unroll
        for (int q = 0; q < 4; q++) rB[q] = *(const uint4*)(gB + j0 + q * 8);
        mkS = *(const uint2*)(mrow + (j0 >> 3));
    };
    auto lwrite = [&](int buf) {
#pragma unroll
        for (int q = 0; q < 4; q++)
            *(uint4*)(&sB[buf][so * 72 + sc + q * 8]) = rB[q];
    };

    const short8 ones = {0x3F80, 0x3F80, 0x3F80, 0x3F80, 0x3F80, 0x3F80, 0x3F80, 0x3F80};
    floatx4 C0 = {0.f, 0.f, 0.f, 0.f}, C1 = C0, C2 = C0, C3 = C0, Cd = C0;

    auto compute = [&](int buf, int j0, uint2 mk) {
        uint m0 = (mk.x >> sh8) & 0xFFu;
        uint m1 = (mk.y >> sh8) & 0xFFu;
        // v/z straight from global (L1-hot) — not the LDS pipe
        float4 va = *(const float4*)(vp + j0 + sh8);
        float4 vb = *(const float4*)(vp + j0 + sh8 + 4);
        float4 vc = *(const float4*)(vp + j0 + 32 + sh8);
        float4 vd = *(const float4*)(vp + j0 + 32 + sh8 + 4);
        float4 za = *(const float4*)(zp + j0 + sh8);
        float4 zb = *(const float4*)(zp + j0 + sh8 + 4);
        float4 zc = *(const float4*)(zp + j0 + 32 + sh8);
        float4 zd = *(const float4*)(zp + j0 + 32 + sh8 + 4);
        short8 a0 = pgen8(va, vb, za, zb, m0, ui, wi, ti);
        short8 a1 = pgen8(vc, vd, zc, zd, m1, ui, wi, ti);
        const ushort* base = &sB[buf][0];
        short8 b00 = *(const short8*)(base + (0  + lm) * 72 + sh8);
        short8 b10 = *(const short8*)(base + (16 + lm) * 72 + sh8);
        short8 b20 = *(const short8*)(base + (32 + lm) * 72 + sh8);
        short8 b30 = *(const short8*)(base + (48 + lm) * 72 + sh8);
        Cd = __builtin_amdgcn_mfma_f32_16x16x32_bf16(a0, ones, Cd, 0, 0, 0);
        C0 = __builtin_amdgcn_mfma_f32_16x16x32_bf16(a0, b00, C0, 0, 0, 0);
        C1 = __builtin_amdgcn_mfma_f32_16x16x32_bf16(a0, b10, C1, 0, 0, 0);
        C2 = __builtin_amdgcn_mfma_f32_16x16x32_bf16(a0, b20, C2, 0, 0, 0);
        C3 = __builtin_amdgcn_mfma_f32_16x16x32_bf16(a0, b30, C3, 0, 0, 0);
        short8 b01 = *(const short8*)(base + (0  + lm) * 72 + 32 + sh8);
        short8 b11 = *(const short8*)(base + (16 + lm) * 72 + 32 + sh8);
        short8 b21 = *(const short8*)(base + (32 + lm) * 72 + 32 + sh8);
        short8 b31 = *(const short8*)(base + (48 + lm) * 72 + 32 + sh8);
        Cd = __builtin_amdgcn_mfma_f32_16x16x32_bf16(a1, ones, Cd, 0, 0, 0);
        C0 = __builtin_amdgcn_mfma_f32_16x16x32_bf16(a1, b01, C0, 0, 0, 0);
        C1 = __builtin_amdgcn_mfma_f32_16x16x32_bf16(a1, b11, C1, 0, 0, 0);
        C2 = __builtin_amdgcn_mfma_f32_16x16x32_bf16(a1, b21, C2, 0, 0, 0);
        C3 = __builtin_amdgcn_mfma_f32_16x16x32_bf16(a1, b31, C3, 0, 0, 0);
    };

    // prologue: stage tile 0, prefetch tile 1 into registers
    gload(0);
    lwrite(0);
    uint2 mk0 = mkS;
    gload(64);
    __syncthreads();

    for (int it = 0; it < 64; it++) {
        compute(it & 1, it * 64, mk0);
        if (it < 63) {
            __syncthreads();                 // all readers of buf[(it+1)&1] done
            lwrite((it + 1) & 1);
            mk0 = mkS;
            gload(((it + 2) & 63) * 64);     // in flight across next compute
            __syncthreads();                 // writes visible
        }
    }

    // epilogue: normalize, elu, store
    const int isbf = detect_bf16(hraw);
#pragma unroll
    for (int r = 0; r < 4; r++) {
        int row = ibase + wid * 16 + lq * 4 + r;
        float inv = 1.f / Cd[r];
        float x0 = C0[r] * inv; x0 = (x0 > 0.f) ? x0 : __expf(x0) - 1.f;
        float x1 = C1[r] * inv; x1 = (x1 > 0.f) ? x1 : __expf(x1) - 1.f;
        float x2 = C2[r] * inv; x2 = (x2 > 0.f) ? x2 : __expf(x2) - 1.f;
        float x3 = C3[r] * inv; x3 = (x3 > 0.f) ? x3 : __expf(x3) - 1.f;
        size_t base = (size_t)row * (NH * FOUT) + head * FOUT + lm;
        if (isbf) {
            ushort* o = (ushort*)outv;
            o[base + 0]  = f2bf(x0);
            o[base + 16] = f2bf(x1);
            o[base + 32] = f2bf(x2);
            o[base + 48] = f2bf(x3);
        } else {
            float* o = (float*)outv;
            o[base + 0]  = x0;
            o[base + 16] = x1;
            o[base + 32] = x2;
            o[base + 48] = x3;
        }
    }
}

extern "C" void kernel_launch(void* const* d_in, const int* in_sizes, int n_in,
                              void* d_out, int out_size, void* d_ws, size_t ws_size,
                              hipStream_t stream)
{
    const void* hraw = d_in[0];
    const int*  mask = (const int*)d_in[1];
    const void* Wraw = d_in[2];
    const void* bWr  = d_in[3];
    const void* alr  = d_in[4];
    const void* arr  = d_in[5];
    const void* bAr  = d_in[6];

    char* w = (char*)d_ws;
    ushort* bh   = (ushort*)w;                  w += (size_t)NN * FIN * 2;        // 4 MB
    ushort* WT   = (ushort*)w;                  w += (size_t)NH * FOUT * FIN * 2; // 512 KB
    ushort* WhT  = (ushort*)w;                  w += (size_t)NH * FOUT * NN * 2;  // 4 MB
    float*  el   = (float*)w;                   w += (size_t)NH * NN * 4;
    float*  er   = (float*)w;                   w += (size_t)NH * NN * 4;
    float*  Kh   = (float*)w;                   w += 64;
    float*  vt   = (float*)w;                   w += (size_t)NH * NN * 4;
    float*  zt   = (float*)w;                   w += (size_t)NH * NN * 4;
    uchar*  mb   = (uchar*)w;                   w += (size_t)NN * 512;            // 2 MB

    prep_kernel<<<PM_BLKS + CV_BLKS + TW_BLKS, 256, 0, stream>>>(
        mask, mb, hraw, bh, Wraw, WT);
    wh_kernel<<<dim3(NN / 64, NH), 256, 0, stream>>>(bh, WT, bWr, alr, arr, bAr,
                                                     (const ushort*)hraw, WhT, el, er);
    khv_kernel<<<64, 256, 0, stream>>>(er, Kh, vt, zt);
    attn_kernel<<<NN / 32 * NH, 128, 0, stream>>>(mb, WhT, el, Kh, vt, zt,
                                                  (const ushort*)hraw, d_out);
}

// Round 12
// 196.541 us; speedup vs baseline: 1.5600x; 1.5600x over previous
//
#include <hip/hip_runtime.h>
#include <hip/hip_bf16.h>

#define NN 4096
#define FIN 512
#define FOUT 64
#define NH 8
#define ALPHA 0.2f

typedef unsigned int uint;
typedef unsigned short ushort;
typedef unsigned char uchar;
typedef unsigned long long ull;
typedef __attribute__((ext_vector_type(8))) short short8;
typedef __attribute__((ext_vector_type(4))) float floatx4;

__device__ __forceinline__ float bf2f(ushort s) { return __uint_as_float(((uint)s) << 16); }
__device__ __forceinline__ ushort f2bf(float f) {
    uint u = __float_as_uint(f);
    u += 0x7fffu + ((u >> 16) & 1u);   // RNE
    return (ushort)(u >> 16);
}

// inline dtype probe: wave-uniform, deterministic (same 64 samples everywhere)
__device__ __forceinline__ int detect_bf16(const ushort* __restrict__ hraw) {
    int lane = threadIdx.x & 63;
    float a = fabsf(bf2f(hraw[2 * lane]));
    ull bal = __ballot(a >= 1e-3f && a <= 100.0f);
    return __popcll(bal) >= 32;
}

// ---------------------------------------------------------------------------
// Fused prep: [0,8192) packmask | [8192,9216) convert h (8 elem/thread) |
//             [9216,9248) transw   (unchanged from passing rounds)
// ---------------------------------------------------------------------------
#define PM_BLKS 8192
#define CV_BLKS 1024
#define TW_BLKS 32

__global__ __launch_bounds__(256) void prep_kernel(
    const int* __restrict__ mask, uchar* __restrict__ mb,
    const void* __restrict__ hraw, ushort* __restrict__ bh,
    const void* __restrict__ Wraw, ushort* __restrict__ WT)
{
    const int b = blockIdx.x, t = threadIdx.x;
    if (b < PM_BLKS) {
        size_t gid = (size_t)b * 256 + t;
        const int* p = mask + gid * 8;
        int4 aa = *(const int4*)p;
        int4 bb = *(const int4*)(p + 4);
        uint by = (uint)(aa.x > 0)        | ((uint)(aa.y > 0) << 1)
                | ((uint)(aa.z > 0) << 2) | ((uint)(aa.w > 0) << 3)
                | ((uint)(bb.x > 0) << 4) | ((uint)(bb.y > 0) << 5)
                | ((uint)(bb.z > 0) << 6) | ((uint)(bb.w > 0) << 7);
        mb[gid] = (uchar)by;
    } else if (b < PM_BLKS + CV_BLKS) {
        int isbf = detect_bf16((const ushort*)hraw);
        size_t e0 = ((size_t)(b - PM_BLKS) * 256 + t) * 8;
        if (isbf) {
            *(uint4*)(bh + e0) = *(const uint4*)((const ushort*)hraw + e0);
        } else {
            const float* s = (const float*)hraw + e0;
            float4 f0 = *(const float4*)s;
            float4 f1 = *(const float4*)(s + 4);
            uint4 o;
            o.x = (uint)f2bf(f0.x) | ((uint)f2bf(f0.y) << 16);
            o.y = (uint)f2bf(f0.z) | ((uint)f2bf(f0.w) << 16);
            o.z = (uint)f2bf(f1.x) | ((uint)f2bf(f1.y) << 16);
            o.w = (uint)f2bf(f1.z) | ((uint)f2bf(f1.w) << 16);
            *(uint4*)(bh + e0) = o;
        }
    } else {
        int isbf = detect_bf16((const ushort*)hraw);
        int b2 = b - PM_BLKS - CV_BLKS;
        int h = b2 >> 2, kq = b2 & 3;
        int o = t & 63, sub = t >> 6;
        int kbase = kq * 128 + sub * 32;
        uint pk[16];
#pragma unroll
        for (int kk = 0; kk < 32; kk += 2) {
            float v0, v1;
            size_t s0 = ((size_t)h * FIN + kbase + kk) * FOUT + o;
            size_t s1 = s0 + FOUT;
            if (isbf) { v0 = bf2f(((const ushort*)Wraw)[s0]); v1 = bf2f(((const ushort*)Wraw)[s1]); }
            else      { v0 = ((const float*)Wraw)[s0];        v1 = ((const float*)Wraw)[s1]; }
            pk[kk >> 1] = (uint)f2bf(v0) | ((uint)f2bf(v1) << 16);
        }
        ushort* dst = WT + ((size_t)h * FOUT + o) * FIN + kbase;
#pragma unroll
        for (int q = 0; q < 4; q++)
            *(uint4*)(dst + q * 8) = make_uint4(pk[q*4], pk[q*4+1], pk[q*4+2], pk[q*4+3]);
    }
}

// per-head packed table: Kh = max_j er'; vz[j] = (bf16 e^{er-Kh}, bf16 e^{a(er-Kh)})
__global__ __launch_bounds__(256) void khv_kernel(const float* __restrict__ er,
                                                  float* __restrict__ Kh,
                                                  uint* __restrict__ vzt) {
    __shared__ float red[256];
    int h = blockIdx.x >> 3, sl = blockIdx.x & 7, t = threadIdx.x;
    float m = -3.0e38f;
    for (int j = t; j < NN; j += 256) m = fmaxf(m, er[(size_t)h * NN + j]);
    red[t] = m;
    __syncthreads();
    for (int s = 128; s >= 1; s >>= 1) {
        if (t < s) red[t] = fmaxf(red[t], red[t + s]);
        __syncthreads();
    }
    float kh = red[0];
    if (t == 0 && sl == 0) Kh[h] = kh;
    int j = sl * 512 + t;
#pragma unroll
    for (int q = 0; q < 2; q++, j += 256) {
        float d = er[(size_t)h * NN + j] - kh;
        vzt[(size_t)h * NN + j] = (uint)f2bf(__expf(d))
                                | ((uint)f2bf(__expf(ALPHA * d)) << 16);
    }
}

// ---------------------------------------------------------------------------
// Stage 1 (MFMA): Wh = h*W + bW; WhT[h][o][n] bf16; el/er dots (unchanged)
// ---------------------------------------------------------------------------
__global__ __launch_bounds__(256) void wh_kernel(
    const ushort* __restrict__ hmat, const ushort* __restrict__ WT,
    const void* __restrict__ bWr, const void* __restrict__ alr,
    const void* __restrict__ arr, const void* __restrict__ bAr,
    const ushort* __restrict__ hraw,
    ushort* __restrict__ WhT, float* __restrict__ el, float* __restrict__ er)
{
    __shared__ __align__(16) ushort sT[64][72];
    const int t = threadIdx.x, lane = t & 63, wid = t >> 6;
    const int head = blockIdx.y, rbase = blockIdx.x * 64;
    const int lm = lane & 15, lq = lane >> 4;

    floatx4 C[4];
#pragma unroll
    for (int cg = 0; cg < 4; cg++) C[cg] = (floatx4){0.f, 0.f, 0.f, 0.f};

    const ushort* Ap = hmat + (size_t)(rbase + wid * 16 + lm) * FIN + lq * 8;
    const ushort* Bp = WT + (size_t)head * FOUT * FIN + (size_t)lm * FIN + lq * 8;

#pragma unroll
    for (int kc = 0; kc < 16; kc++) {
        short8 a = *(const short8*)(Ap + kc * 32);
#pragma unroll
        for (int cg = 0; cg < 4; cg++) {
            short8 b = *(const short8*)(Bp + (size_t)cg * 16 * FIN + kc * 32);
            C[cg] = __builtin_amdgcn_mfma_f32_16x16x32_bf16(a, b, C[cg], 0, 0, 0);
        }
    }

    const int isbf = detect_bf16(hraw);
    float bA = isbf ? bf2f(((const ushort*)bAr)[head]) : ((const float*)bAr)[head];
    float pel[4] = {0.f, 0.f, 0.f, 0.f}, per[4] = {0.f, 0.f, 0.f, 0.f};
#pragma unroll
    for (int cg = 0; cg < 4; cg++) {
        int o = head * FOUT + cg * 16 + lm;
        float bw = isbf ? bf2f(((const ushort*)bWr)[o]) : ((const float*)bWr)[o];
        float av = isbf ? bf2f(((const ushort*)alr)[o]) : ((const float*)alr)[o];
        float rv = isbf ? bf2f(((const ushort*)arr)[o]) : ((const float*)arr)[o];
        ushort pk[4];
#pragma unroll
        for (int r = 0; r < 4; r++) {
            float v = C[cg][r] + bw;
            pel[r] += v * av;
            per[r] += v * rv;
            pk[r] = f2bf(v);
        }
        ushort4 p4; p4.x = pk[0]; p4.y = pk[1]; p4.z = pk[2]; p4.w = pk[3];
        *(ushort4*)(&sT[cg * 16 + lm][wid * 16 + lq * 4]) = p4;
    }
#pragma unroll
    for (int off = 1; off < 16; off <<= 1) {
#pragma unroll
        for (int r = 0; r < 4; r++) {
            pel[r] += __shfl_xor(pel[r], off);
            per[r] += __shfl_xor(per[r], off);
        }
    }
    if (lm == 0) {
#pragma unroll
        for (int r = 0; r < 4; r++) {
            int row = rbase + wid * 16 + lq * 4 + r;
            el[(size_t)head * NN + row] = pel[r];
            er[(size_t)head * NN + row] = per[r] + bA;
        }
    }
    __syncthreads();
    {
        int o = t >> 2, ch = t & 3;
        uint4 v0 = *(const uint4*)(&sT[o][ch * 16]);
        uint4 v1 = *(const uint4*)(&sT[o][ch * 16 + 8]);
        ushort* d = WhT + ((size_t)head * FOUT + o) * NN + rbase + ch * 16;
        *(uint4*)d = v0;
        *(uint4*)(d + 8) = v1;
    }
}

// ---------------------------------------------------------------------------
// Stage 2 (R12): R8's proven 2-barrier LDS-dbuf skeleton, byte-identical
// structure; ONLY delta: v/z staged/read as ONE packed bf16-pair uint
// (halves the v/z LDS traffic that dominates R8's 47 us LDS-pipe busy).
// ---------------------------------------------------------------------------
__device__ __forceinline__ uint ppair(uint vz0, uint vz1,
                                      uint m2, float ui, float wi, float ti) {
    float v0 = __uint_as_float(vz0 << 16);
    float z0 = __uint_as_float(vz0 & 0xffff0000u);
    float v1 = __uint_as_float(vz1 << 16);
    float z1 = __uint_as_float(vz1 & 0xffff0000u);
    float p0 = (v0 >= ti) ? ui * v0 : wi * z0;
    float p1 = (v1 >= ti) ? ui * v1 : wi * z1;
    uint k0 = (uint)0 - (m2 & 1u);
    uint k1 = (uint)0 - ((m2 >> 1) & 1u);
    p0 = __uint_as_float(__float_as_uint(p0) & k0);
    p1 = __uint_as_float(__float_as_uint(p1) & k1);
    __hip_bfloat162 r = __float22bfloat162_rn(make_float2(p0, p1));
    return *(uint*)&r;
}

__device__ __forceinline__ short8 pgen8(uint4 wA, uint4 wB,
                                        uint mby, float ui, float wi, float ti) {
    union { uint4 u; short8 s; } c;
    c.u.x = ppair(wA.x, wA.y, mby,      ui, wi, ti);
    c.u.y = ppair(wA.z, wA.w, mby >> 2, ui, wi, ti);
    c.u.z = ppair(wB.x, wB.y, mby >> 4, ui, wi, ti);
    c.u.w = ppair(wB.z, wB.w, mby >> 6, ui, wi, ti);
    return c.s;
}

__global__ __launch_bounds__(256, 2) void attn_kernel(
    const uchar* __restrict__ mb,      // [NN][512] bitmask
    const ushort* __restrict__ WhT,    // [H][FOUT][NN] bf16
    const float* __restrict__ el, const float* __restrict__ Kh,
    const uint* __restrict__ vzt,      // [H][NN] packed (bf16 v, bf16 z)
    const ushort* __restrict__ hraw,
    void* __restrict__ outv)
{
    __shared__ __align__(16) ushort sB[2][64 * 72];  // B tile [o][j], dbuf
    __shared__ __align__(16) uint svz[2][64];        // packed v/z slice, dbuf

    const int t = threadIdx.x, lane = t & 63, wid = t >> 6;
    const int b = blockIdx.x;
    const int head = b & 7;                       // XCD swizzle
    const int ibase = ((b >> 3)) * 64;
    const int lm = lane & 15, lq = lane >> 4;
    const int sh8 = lq * 8;

    // per-lane row constants
    const float kh = Kh[head];
    const float x = el[(size_t)head * NN + ibase + wid * 16 + lm] + kh;
    const float Mi = fmaxf(x, ALPHA * x);
    const float ui = __expf(x - Mi);
    const float wi = __expf(ALPHA * x - Mi);
    const float ti = __expf(-x);

    const uint* gvz = vzt + (size_t)head * NN;
    const uchar* mrow = mb + (size_t)(ibase + wid * 16 + lm) * 512;

    // staging assignment: thread t -> B row so, col group sc (32 B = 2 uint4)
    const int so = t >> 2;
    const int sc = (t & 3) * 16;
    const ushort* gB = WhT + ((size_t)head * FOUT + so) * NN + sc;

    uint4 r0, r1; uint rvz = 0; uint2 mk_stage;

    auto gload = [&](int j0) {
        r0 = *(const uint4*)(gB + j0);
        r1 = *(const uint4*)(gB + j0 + 8);
        if (t < 64) rvz = gvz[j0 + t];
        mk_stage = *(const uint2*)(mrow + (j0 >> 3));
    };
    auto lwrite = [&](int buf) {
        *(uint4*)(&sB[buf][so * 72 + sc]) = r0;
        *(uint4*)(&sB[buf][so * 72 + sc + 8]) = r1;
        if (t < 64) svz[buf][t] = rvz;
    };

    const short8 ones = {0x3F80, 0x3F80, 0x3F80, 0x3F80, 0x3F80, 0x3F80, 0x3F80, 0x3F80};
    floatx4 C0 = {0.f, 0.f, 0.f, 0.f}, C1 = C0, C2 = C0, C3 = C0, Cd = C0;

    auto compute = [&](int buf, uint2 mk) {
        uint m0 = (mk.x >> sh8) & 0xFFu;
        uint m1 = (mk.y >> sh8) & 0xFFu;
        uint4 wA0 = *(const uint4*)(&svz[buf][sh8]);
        uint4 wB0 = *(const uint4*)(&svz[buf][sh8 + 4]);
        uint4 wA1 = *(const uint4*)(&svz[buf][32 + sh8]);
        uint4 wB1 = *(const uint4*)(&svz[buf][32 + sh8 + 4]);
        short8 a0 = pgen8(wA0, wB0, m0, ui, wi, ti);
        short8 a1 = pgen8(wA1, wB1, m1, ui, wi, ti);
        const ushort* base = &sB[buf][0];
        short8 b00 = *(const short8*)(base + (0  + lm) * 72 + sh8);
        short8 b10 = *(const short8*)(base + (16 + lm) * 72 + sh8);
        short8 b20 = *(const short8*)(base + (32 + lm) * 72 + sh8);
        short8 b30 = *(const short8*)(base + (48 + lm) * 72 + sh8);
        Cd = __builtin_amdgcn_mfma_f32_16x16x32_bf16(a0, ones, Cd, 0, 0, 0);
        C0 = __builtin_amdgcn_mfma_f32_16x16x32_bf16(a0, b00, C0, 0, 0, 0);
        C1 = __builtin_amdgcn_mfma_f32_16x16x32_bf16(a0, b10, C1, 0, 0, 0);
        C2 = __builtin_amdgcn_mfma_f32_16x16x32_bf16(a0, b20, C2, 0, 0, 0);
        C3 = __builtin_amdgcn_mfma_f32_16x16x32_bf16(a0, b30, C3, 0, 0, 0);
        short8 b01 = *(const short8*)(base + (0  + lm) * 72 + 32 + sh8);
        short8 b11 = *(const short8*)(base + (16 + lm) * 72 + 32 + sh8);
        short8 b21 = *(const short8*)(base + (32 + lm) * 72 + 32 + sh8);
        short8 b31 = *(const short8*)(base + (48 + lm) * 72 + 32 + sh8);
        Cd = __builtin_amdgcn_mfma_f32_16x16x32_bf16(a1, ones, Cd, 0, 0, 0);
        C0 = __builtin_amdgcn_mfma_f32_16x16x32_bf16(a1, b01, C0, 0, 0, 0);
        C1 = __builtin_amdgcn_mfma_f32_16x16x32_bf16(a1, b11, C1, 0, 0, 0);
        C2 = __builtin_amdgcn_mfma_f32_16x16x32_bf16(a1, b21, C2, 0, 0, 0);
        C3 = __builtin_amdgcn_mfma_f32_16x16x32_bf16(a1, b31, C3, 0, 0, 0);
    };

    // prologue: stage tile 0, prefetch tile 1 into registers
    gload(0);
    lwrite(0);
    uint2 mk0 = mk_stage;
    gload(64);
    __syncthreads();

    for (int it = 0; it < 64; it++) {
        compute(it & 1, mk0);
        if (it < 63) {
            __syncthreads();                 // all readers of buf[(it+1)&1] done
            lwrite((it + 1) & 1);
            mk0 = mk_stage;
            gload(((it + 2) & 63) * 64);     // in flight across next compute
            __syncthreads();                 // writes visible
        }
    }

    // epilogue: normalize, elu, store
    const int isbf = detect_bf16(hraw);
#pragma unroll
    for (int r = 0; r < 4; r++) {
        int row = ibase + wid * 16 + lq * 4 + r;
        float inv = 1.f / Cd[r];
        float x0 = C0[r] * inv; x0 = (x0 > 0.f) ? x0 : __expf(x0) - 1.f;
        float x1 = C1[r] * inv; x1 = (x1 > 0.f) ? x1 : __expf(x1) - 1.f;
        float x2 = C2[r] * inv; x2 = (x2 > 0.f) ? x2 : __expf(x2) - 1.f;
        float x3 = C3[r] * inv; x3 = (x3 > 0.f) ? x3 : __expf(x3) - 1.f;
        size_t base = (size_t)row * (NH * FOUT) + head * FOUT + lm;
        if (isbf) {
            ushort* o = (ushort*)outv;
            o[base + 0]  = f2bf(x0);
            o[base + 16] = f2bf(x1);
            o[base + 32] = f2bf(x2);
            o[base + 48] = f2bf(x3);
        } else {
            float* o = (float*)outv;
            o[base + 0]  = x0;
            o[base + 16] = x1;
            o[base + 32] = x2;
            o[base + 48] = x3;
        }
    }
}

extern "C" void kernel_launch(void* const* d_in, const int* in_sizes, int n_in,
                              void* d_out, int out_size, void* d_ws, size_t ws_size,
                              hipStream_t stream)
{
    const void* hraw = d_in[0];
    const int*  mask = (const int*)d_in[1];
    const void* Wraw = d_in[2];
    const void* bWr  = d_in[3];
    const void* alr  = d_in[4];
    const void* arr  = d_in[5];
    const void* bAr  = d_in[6];

    char* w = (char*)d_ws;
    ushort* bh   = (ushort*)w;                  w += (size_t)NN * FIN * 2;        // 4 MB
    ushort* WT   = (ushort*)w;                  w += (size_t)NH * FOUT * FIN * 2; // 512 KB
    ushort* WhT  = (ushort*)w;                  w += (size_t)NH * FOUT * NN * 2;  // 4 MB
    float*  el   = (float*)w;                   w += (size_t)NH * NN * 4;
    float*  er   = (float*)w;                   w += (size_t)NH * NN * 4;
    float*  Kh   = (float*)w;                   w += 64;
    uint*   vzt  = (uint*)w;                    w += (size_t)NH * NN * 4;         // 128 KB
    uchar*  mb   = (uchar*)w;                   w += (size_t)NN * 512;            // 2 MB

    prep_kernel<<<PM_BLKS + CV_BLKS + TW_BLKS, 256, 0, stream>>>(
        mask, mb, hraw, bh, Wraw, WT);
    wh_kernel<<<dim3(NN / 64, NH), 256, 0, stream>>>(bh, WT, bWr, alr, arr, bAr,
                                                     (const ushort*)hraw, WhT, el, er);
    khv_kernel<<<64, 256, 0, stream>>>(er, Kh, vzt);
    attn_kernel<<<NN / 64 * NH, 256, 0, stream>>>(mb, WhT, el, Kh, vzt,
                                                  (const ushort*)hraw, d_out);
}

// Round 13
// 192.198 us; speedup vs baseline: 1.5953x; 1.0226x over previous
//
#include <hip/hip_runtime.h>
#include <hip/hip_bf16.h>

#define NN 4096
#define FIN 512
#define FOUT 64
#define NH 8
#define ALPHA 0.2f

typedef unsigned int uint;
typedef unsigned short ushort;
typedef unsigned char uchar;
typedef unsigned long long ull;
typedef __attribute__((ext_vector_type(8))) short short8;
typedef __attribute__((ext_vector_type(4))) float floatx4;

__device__ __forceinline__ float bf2f(ushort s) { return __uint_as_float(((uint)s) << 16); }
__device__ __forceinline__ ushort f2bf(float f) {
    uint u = __float_as_uint(f);
    u += 0x7fffu + ((u >> 16) & 1u);   // RNE
    return (ushort)(u >> 16);
}

// inline dtype probe: wave-uniform, deterministic (same 64 samples everywhere)
__device__ __forceinline__ int detect_bf16(const ushort* __restrict__ hraw) {
    int lane = threadIdx.x & 63;
    float a = fabsf(bf2f(hraw[2 * lane]));
    ull bal = __ballot(a >= 1e-3f && a <= 100.0f);
    return __popcll(bal) >= 32;
}

// ---------------------------------------------------------------------------
// Fused prep: [0,8192) packmask | [8192,9216) convert h (8 elem/thread) |
//             [9216,9248) transw   (unchanged from passing rounds)
// ---------------------------------------------------------------------------
#define PM_BLKS 8192
#define CV_BLKS 1024
#define TW_BLKS 32

__global__ __launch_bounds__(256) void prep_kernel(
    const int* __restrict__ mask, uchar* __restrict__ mb,
    const void* __restrict__ hraw, ushort* __restrict__ bh,
    const void* __restrict__ Wraw, ushort* __restrict__ WT)
{
    const int b = blockIdx.x, t = threadIdx.x;
    if (b < PM_BLKS) {
        size_t gid = (size_t)b * 256 + t;
        const int* p = mask + gid * 8;
        int4 aa = *(const int4*)p;
        int4 bb = *(const int4*)(p + 4);
        uint by = (uint)(aa.x > 0)        | ((uint)(aa.y > 0) << 1)
                | ((uint)(aa.z > 0) << 2) | ((uint)(aa.w > 0) << 3)
                | ((uint)(bb.x > 0) << 4) | ((uint)(bb.y > 0) << 5)
                | ((uint)(bb.z > 0) << 6) | ((uint)(bb.w > 0) << 7);
        mb[gid] = (uchar)by;
    } else if (b < PM_BLKS + CV_BLKS) {
        int isbf = detect_bf16((const ushort*)hraw);
        size_t e0 = ((size_t)(b - PM_BLKS) * 256 + t) * 8;
        if (isbf) {
            *(uint4*)(bh + e0) = *(const uint4*)((const ushort*)hraw + e0);
        } else {
            const float* s = (const float*)hraw + e0;
            float4 f0 = *(const float4*)s;
            float4 f1 = *(const float4*)(s + 4);
            uint4 o;
            o.x = (uint)f2bf(f0.x) | ((uint)f2bf(f0.y) << 16);
            o.y = (uint)f2bf(f0.z) | ((uint)f2bf(f0.w) << 16);
            o.z = (uint)f2bf(f1.x) | ((uint)f2bf(f1.y) << 16);
            o.w = (uint)f2bf(f1.z) | ((uint)f2bf(f1.w) << 16);
            *(uint4*)(bh + e0) = o;
        }
    } else {
        int isbf = detect_bf16((const ushort*)hraw);
        int b2 = b - PM_BLKS - CV_BLKS;
        int h = b2 >> 2, kq = b2 & 3;
        int o = t & 63, sub = t >> 6;
        int kbase = kq * 128 + sub * 32;
        uint pk[16];
#pragma unroll
        for (int kk = 0; kk < 32; kk += 2) {
            float v0, v1;
            size_t s0 = ((size_t)h * FIN + kbase + kk) * FOUT + o;
            size_t s1 = s0 + FOUT;
            if (isbf) { v0 = bf2f(((const ushort*)Wraw)[s0]); v1 = bf2f(((const ushort*)Wraw)[s1]); }
            else      { v0 = ((const float*)Wraw)[s0];        v1 = ((const float*)Wraw)[s1]; }
            pk[kk >> 1] = (uint)f2bf(v0) | ((uint)f2bf(v1) << 16);
        }
        ushort* dst = WT + ((size_t)h * FOUT + o) * FIN + kbase;
#pragma unroll
        for (int q = 0; q < 4; q++)
            *(uint4*)(dst + q * 8) = make_uint4(pk[q*4], pk[q*4+1], pk[q*4+2], pk[q*4+3]);
    }
}

// per-head tables: Kh = max_j er'; v_j = e^{er-Kh}; z_j = e^{alpha(er-Kh)}
__global__ __launch_bounds__(256) void khv_kernel(const float* __restrict__ er,
                                                  float* __restrict__ Kh,
                                                  float* __restrict__ vt,
                                                  float* __restrict__ zt) {
    __shared__ float red[256];
    int h = blockIdx.x >> 3, sl = blockIdx.x & 7, t = threadIdx.x;
    float m = -3.0e38f;
    for (int j = t; j < NN; j += 256) m = fmaxf(m, er[(size_t)h * NN + j]);
    red[t] = m;
    __syncthreads();
    for (int s = 128; s >= 1; s >>= 1) {
        if (t < s) red[t] = fmaxf(red[t], red[t + s]);
        __syncthreads();
    }
    float kh = red[0];
    if (t == 0 && sl == 0) Kh[h] = kh;
    int j = sl * 512 + t;
#pragma unroll
    for (int q = 0; q < 2; q++, j += 256) {
        float d = er[(size_t)h * NN + j] - kh;
        vt[(size_t)h * NN + j] = __expf(d);
        zt[(size_t)h * NN + j] = __expf(ALPHA * d);
    }
}

// ---------------------------------------------------------------------------
// Stage 1 (MFMA): Wh = h*W + bW; WhT[h][o][n] bf16; el/er dots (unchanged)
// ---------------------------------------------------------------------------
__global__ __launch_bounds__(256) void wh_kernel(
    const ushort* __restrict__ hmat, const ushort* __restrict__ WT,
    const void* __restrict__ bWr, const void* __restrict__ alr,
    const void* __restrict__ arr, const void* __restrict__ bAr,
    const ushort* __restrict__ hraw,
    ushort* __restrict__ WhT, float* __restrict__ el, float* __restrict__ er)
{
    __shared__ __align__(16) ushort sT[64][72];
    const int t = threadIdx.x, lane = t & 63, wid = t >> 6;
    const int head = blockIdx.y, rbase = blockIdx.x * 64;
    const int lm = lane & 15, lq = lane >> 4;

    floatx4 C[4];
#pragma unroll
    for (int cg = 0; cg < 4; cg++) C[cg] = (floatx4){0.f, 0.f, 0.f, 0.f};

    const ushort* Ap = hmat + (size_t)(rbase + wid * 16 + lm) * FIN + lq * 8;
    const ushort* Bp = WT + (size_t)head * FOUT * FIN + (size_t)lm * FIN + lq * 8;

#pragma unroll
    for (int kc = 0; kc < 16; kc++) {
        short8 a = *(const short8*)(Ap + kc * 32);
#pragma unroll
        for (int cg = 0; cg < 4; cg++) {
            short8 b = *(const short8*)(Bp + (size_t)cg * 16 * FIN + kc * 32);
            C[cg] = __builtin_amdgcn_mfma_f32_16x16x32_bf16(a, b, C[cg], 0, 0, 0);
        }
    }

    const int isbf = detect_bf16(hraw);
    float bA = isbf ? bf2f(((const ushort*)bAr)[head]) : ((const float*)bAr)[head];
    float pel[4] = {0.f, 0.f, 0.f, 0.f}, per[4] = {0.f, 0.f, 0.f, 0.f};
#pragma unroll
    for (int cg = 0; cg < 4; cg++) {
        int o = head * FOUT + cg * 16 + lm;
        float bw = isbf ? bf2f(((const ushort*)bWr)[o]) : ((const float*)bWr)[o];
        float av = isbf ? bf2f(((const ushort*)alr)[o]) : ((const float*)alr)[o];
        float rv = isbf ? bf2f(((const ushort*)arr)[o]) : ((const float*)arr)[o];
        ushort pk[4];
#pragma unroll
        for (int r = 0; r < 4; r++) {
            float v = C[cg][r] + bw;
            pel[r] += v * av;
            per[r] += v * rv;
            pk[r] = f2bf(v);
        }
        ushort4 p4; p4.x = pk[0]; p4.y = pk[1]; p4.z = pk[2]; p4.w = pk[3];
        *(ushort4*)(&sT[cg * 16 + lm][wid * 16 + lq * 4]) = p4;
    }
#pragma unroll
    for (int off = 1; off < 16; off <<= 1) {
#pragma unroll
        for (int r = 0; r < 4; r++) {
            pel[r] += __shfl_xor(pel[r], off);
            per[r] += __shfl_xor(per[r], off);
        }
    }
    if (lm == 0) {
#pragma unroll
        for (int r = 0; r < 4; r++) {
            int row = rbase + wid * 16 + lq * 4 + r;
            el[(size_t)head * NN + row] = pel[r];
            er[(size_t)head * NN + row] = per[r] + bA;
        }
    }
    __syncthreads();
    {
        int o = t >> 2, ch = t & 3;
        uint4 v0 = *(const uint4*)(&sT[o][ch * 16]);
        uint4 v1 = *(const uint4*)(&sT[o][ch * 16 + 8]);
        ushort* d = WhT + ((size_t)head * FOUT + o) * NN + rbase + ch * 16;
        *(uint4*)d = v0;
        *(uint4*)(d + 8) = v1;
    }
}

// ---------------------------------------------------------------------------
// Stage 2 (R13): R8's 66-us skeleton byte-identical (float v/z via LDS,
// 2-barrier dbuf). VALU-only deltas: (1) max-trick — e^{lrelu(s)-Mi} =
// max(ui*v, wi*z), identical value, no cmp/cndmask/ti; (2) K-loop unrolled
// by 2 (static buf indices).
// ---------------------------------------------------------------------------
__device__ __forceinline__ uint ppair(float v0, float v1, float z0, float z1,
                                      uint m2, float ui, float wi) {
    float p0 = fmaxf(ui * v0, wi * z0);    // = e^{lrelu(s)-Mi} (alpha<1)
    float p1 = fmaxf(ui * v1, wi * z1);
    uint k0 = (uint)0 - (m2 & 1u);
    uint k1 = (uint)0 - ((m2 >> 1) & 1u);
    p0 = __uint_as_float(__float_as_uint(p0) & k0);
    p1 = __uint_as_float(__float_as_uint(p1) & k1);
    __hip_bfloat162 r = __float22bfloat162_rn(make_float2(p0, p1));
    return *(uint*)&r;
}

__device__ __forceinline__ short8 pgen8(float4 va, float4 vb, float4 za, float4 zb,
                                        uint mby, float ui, float wi) {
    union { uint4 u; short8 s; } c;
    c.u.x = ppair(va.x, va.y, za.x, za.y, mby,      ui, wi);
    c.u.y = ppair(va.z, va.w, za.z, za.w, mby >> 2, ui, wi);
    c.u.z = ppair(vb.x, vb.y, zb.x, zb.y, mby >> 4, ui, wi);
    c.u.w = ppair(vb.z, vb.w, zb.z, zb.w, mby >> 6, ui, wi);
    return c.s;
}

__global__ __launch_bounds__(256, 2) void attn_kernel(
    const uchar* __restrict__ mb,      // [NN][512] bitmask
    const ushort* __restrict__ WhT,    // [H][FOUT][NN] bf16
    const float* __restrict__ el, const float* __restrict__ Kh,
    const float* __restrict__ vt, const float* __restrict__ zt,
    const ushort* __restrict__ hraw,
    void* __restrict__ outv)
{
    __shared__ __align__(16) ushort sB[2][64 * 72];  // B tile [o][j], dbuf
    __shared__ float sv[2][64];
    __shared__ float sz[2][64];

    const int t = threadIdx.x, lane = t & 63, wid = t >> 6;
    const int b = blockIdx.x;
    const int head = b & 7;                       // XCD swizzle
    const int ibase = (b >> 3) * 64;
    const int lm = lane & 15, lq = lane >> 4;
    const int sh8 = lq * 8;

    // per-lane row constants (max-trick: only ui, wi needed)
    const float kh = Kh[head];
    const float x = el[(size_t)head * NN + ibase + wid * 16 + lm] + kh;
    const float Mi = fmaxf(x, ALPHA * x);
    const float ui = __expf(x - Mi);
    const float wi = __expf(ALPHA * x - Mi);

    // staging assignment: thread t -> B row so, col group sc (32 B = 2 uint4)
    const int so = t >> 2;
    const int sc = (t & 3) * 16;
    const ushort* gB = WhT + ((size_t)head * FOUT + so) * NN + sc;
    const float* gvt = vt + (size_t)head * NN;
    const float* gzt = zt + (size_t)head * NN;
    const uchar* mrow = mb + (size_t)(ibase + wid * 16 + lm) * 512;

    uint4 r0, r1; float rvz = 0.f; uint2 mk_stage;

    auto gload = [&](int j0) {
        r0 = *(const uint4*)(gB + j0);
        r1 = *(const uint4*)(gB + j0 + 8);
        if (t < 128) rvz = (t < 64) ? gvt[j0 + t] : gzt[j0 + t - 64];
        mk_stage = *(const uint2*)(mrow + (j0 >> 3));
    };
    auto lwrite = [&](int buf) {
        *(uint4*)(&sB[buf][so * 72 + sc]) = r0;
        *(uint4*)(&sB[buf][so * 72 + sc + 8]) = r1;
        if (t < 128) { if (t < 64) sv[buf][t] = rvz; else sz[buf][t - 64] = rvz; }
    };

    const short8 ones = {0x3F80, 0x3F80, 0x3F80, 0x3F80, 0x3F80, 0x3F80, 0x3F80, 0x3F80};
    floatx4 C0 = {0.f, 0.f, 0.f, 0.f}, C1 = C0, C2 = C0, C3 = C0, Cd = C0;

    auto compute = [&](int buf, uint2 mk) {
        uint m0 = (mk.x >> sh8) & 0xFFu;
        uint m1 = (mk.y >> sh8) & 0xFFu;
        float4 va = *(const float4*)(&sv[buf][sh8]);
        float4 vb = *(const float4*)(&sv[buf][sh8 + 4]);
        float4 vc = *(const float4*)(&sv[buf][32 + sh8]);
        float4 vd = *(const float4*)(&sv[buf][36 + sh8]);
        float4 za = *(const float4*)(&sz[buf][sh8]);
        float4 zb = *(const float4*)(&sz[buf][sh8 + 4]);
        float4 zc = *(const float4*)(&sz[buf][32 + sh8]);
        float4 zd = *(const float4*)(&sz[buf][36 + sh8]);
        short8 a0 = pgen8(va, vb, za, zb, m0, ui, wi);
        short8 a1 = pgen8(vc, vd, zc, zd, m1, ui, wi);
        const ushort* base = &sB[buf][0];
        short8 b00 = *(const short8*)(base + (0  + lm) * 72 + sh8);
        short8 b10 = *(const short8*)(base + (16 + lm) * 72 + sh8);
        short8 b20 = *(const short8*)(base + (32 + lm) * 72 + sh8);
        short8 b30 = *(const short8*)(base + (48 + lm) * 72 + sh8);
        Cd = __builtin_amdgcn_mfma_f32_16x16x32_bf16(a0, ones, Cd, 0, 0, 0);
        C0 = __builtin_amdgcn_mfma_f32_16x16x32_bf16(a0, b00, C0, 0, 0, 0);
        C1 = __builtin_amdgcn_mfma_f32_16x16x32_bf16(a0, b10, C1, 0, 0, 0);
        C2 = __builtin_amdgcn_mfma_f32_16x16x32_bf16(a0, b20, C2, 0, 0, 0);
        C3 = __builtin_amdgcn_mfma_f32_16x16x32_bf16(a0, b30, C3, 0, 0, 0);
        short8 b01 = *(const short8*)(base + (0  + lm) * 72 + 32 + sh8);
        short8 b11 = *(const short8*)(base + (16 + lm) * 72 + 32 + sh8);
        short8 b21 = *(const short8*)(base + (32 + lm) * 72 + 32 + sh8);
        short8 b31 = *(const short8*)(base + (48 + lm) * 72 + 32 + sh8);
        Cd = __builtin_amdgcn_mfma_f32_16x16x32_bf16(a1, ones, Cd, 0, 0, 0);
        C0 = __builtin_amdgcn_mfma_f32_16x16x32_bf16(a1, b01, C0, 0, 0, 0);
        C1 = __builtin_amdgcn_mfma_f32_16x16x32_bf16(a1, b11, C1, 0, 0, 0);
        C2 = __builtin_amdgcn_mfma_f32_16x16x32_bf16(a1, b21, C2, 0, 0, 0);
        C3 = __builtin_amdgcn_mfma_f32_16x16x32_bf16(a1, b31, C3, 0, 0, 0);
    };

    // prologue: stage tile 0, prefetch tile 1 into registers
    gload(0);
    lwrite(0);
    uint2 mk0 = mk_stage;
    gload(64);
    __syncthreads();

    // main loop, unrolled x2 (static buf indices) — same barrier schedule as R8
    for (int it = 0; it < 64; it += 2) {
        compute(0, mk0);
        __syncthreads();
        lwrite(1);
        mk0 = mk_stage;
        gload(((it + 2) & 63) * 64);
        __syncthreads();
        compute(1, mk0);
        if (it < 62) {
            __syncthreads();
            lwrite(0);
            mk0 = mk_stage;
            gload(((it + 3) & 63) * 64);
            __syncthreads();
        }
    }

    // epilogue: normalize, elu, store
    const int isbf = detect_bf16(hraw);
#pragma unroll
    for (int r = 0; r < 4; r++) {
        int row = ibase + wid * 16 + lq * 4 + r;
        float inv = 1.f / Cd[r];
        float x0 = C0[r] * inv; x0 = (x0 > 0.f) ? x0 : __expf(x0) - 1.f;
        float x1 = C1[r] * inv; x1 = (x1 > 0.f) ? x1 : __expf(x1) - 1.f;
        float x2 = C2[r] * inv; x2 = (x2 > 0.f) ? x2 : __expf(x2) - 1.f;
        float x3 = C3[r] * inv; x3 = (x3 > 0.f) ? x3 : __expf(x3) - 1.f;
        size_t base = (size_t)row * (NH * FOUT) + head * FOUT + lm;
        if (isbf) {
            ushort* o = (ushort*)outv;
            o[base + 0]  = f2bf(x0);
            o[base + 16] = f2bf(x1);
            o[base + 32] = f2bf(x2);
            o[base + 48] = f2bf(x3);
        } else {
            float* o = (float*)outv;
            o[base + 0]  = x0;
            o[base + 16] = x1;
            o[base + 32] = x2;
            o[base + 48] = x3;
        }
    }
}

extern "C" void kernel_launch(void* const* d_in, const int* in_sizes, int n_in,
                              void* d_out, int out_size, void* d_ws, size_t ws_size,
                              hipStream_t stream)
{
    const void* hraw = d_in[0];
    const int*  mask = (const int*)d_in[1];
    const void* Wraw = d_in[2];
    const void* bWr  = d_in[3];
    const void* alr  = d_in[4];
    const void* arr  = d_in[5];
    const void* bAr  = d_in[6];

    char* w = (char*)d_ws;
    ushort* bh   = (ushort*)w;                  w += (size_t)NN * FIN * 2;        // 4 MB
    ushort* WT   = (ushort*)w;                  w += (size_t)NH * FOUT * FIN * 2; // 512 KB
    ushort* WhT  = (ushort*)w;                  w += (size_t)NH * FOUT * NN * 2;  // 4 MB
    float*  el   = (float*)w;                   w += (size_t)NH * NN * 4;
    float*  er   = (float*)w;                   w += (size_t)NH * NN * 4;
    float*  Kh   = (float*)w;                   w += 64;
    float*  vt   = (float*)w;                   w += (size_t)NH * NN * 4;
    float*  zt   = (float*)w;                   w += (size_t)NH * NN * 4;
    uchar*  mb   = (uchar*)w;                   w += (size_t)NN * 512;            // 2 MB

    prep_kernel<<<PM_BLKS + CV_BLKS + TW_BLKS, 256, 0, stream>>>(
        mask, mb, hraw, bh, Wraw, WT);
    wh_kernel<<<dim3(NN / 64, NH), 256, 0, stream>>>(bh, WT, bWr, alr, arr, bAr,
                                                     (const ushort*)hraw, WhT, el, er);
    khv_kernel<<<64, 256, 0, stream>>>(er, Kh, vt, zt);
    attn_kernel<<<NN / 64 * NH, 256, 0, stream>>>(mb, WhT, el, Kh, vt, zt,
                                                  (const ushort*)hraw, d_out);
}